// Round 3
// baseline (88.191 us; speedup 1.0000x reference)
//
#include <hip/hip_runtime.h>
#include <cstdint>
#include <cstddef>

#define TINV 5.0f
#define C5L2E 7.2134752044448170f   // 5 * log2(e)
#define NROWS 4096
#define DDIM 256
#define MM 8192
#define BM 128
#define BN 128
#define NCS 8
#define COLS_PER_SPLIT 1024
#define TILES_PER_SPLIT 8

typedef __bf16 bf16x8 __attribute__((ext_vector_type(8)));
typedef float f32x4 __attribute__((ext_vector_type(4)));

typedef const void __attribute__((address_space(1)))* gas_ptr;
typedef void __attribute__((address_space(3)))* las_ptr;

// ---------------- normalize: rows of [Z1;Z2] -> unit L2, store bf16 ----------------
__global__ __launch_bounds__(256, 2)
void nrm_kernel(const float* __restrict__ Z1, const float* __restrict__ Z2,
                unsigned short* __restrict__ Zb) {
    const int w = threadIdx.x >> 6, lane = threadIdx.x & 63;
    const int row = blockIdx.x * 4 + w;
    const float* src = row < NROWS ? Z1 + (size_t)row * DDIM
                                   : Z2 + (size_t)(row - NROWS) * DDIM;
    float4 v = reinterpret_cast<const float4*>(src)[lane];
    float ss = v.x*v.x + v.y*v.y + v.z*v.z + v.w*v.w;
    #pragma unroll
    for (int m = 1; m < 64; m <<= 1) ss += __shfl_xor(ss, m, 64);
    float inv = 1.0f / fmaxf(sqrtf(ss), 1e-12f);
    float o[4] = { v.x*inv, v.y*inv, v.z*inv, v.w*inv };
    unsigned short us[4];
    #pragma unroll
    for (int e = 0; e < 4; ++e) {           // RNE f32->bf16 (finite inputs)
        unsigned int b = __builtin_bit_cast(unsigned int, o[e]);
        b += 0x7FFFu + ((b >> 16) & 1u);
        us[e] = (unsigned short)(b >> 16);
    }
    reinterpret_cast<ushort4*>(Zb + (size_t)row * DDIM)[lane] =
        *reinterpret_cast<ushort4*>(us);
}

// ---- stage 128 rows x 256 cols bf16 (64KB contiguous) into LDS, XOR-swizzled ----
__device__ __forceinline__ void stage_tile(const unsigned short* Zb, unsigned short* lds,
                                           int rowStart, int tid) {
    const char* base = reinterpret_cast<const char*>(Zb) + (size_t)rowStart * 512;
    char* lb = reinterpret_cast<char*>(lds);
    #pragma unroll
    for (int it = 0; it < 16; ++it) {
        int L = it * 4096 + tid * 16;     // linear LDS byte offset, lane-contiguous
        int row = L >> 9;                 // 0..127 (512 B per row)
        int inrow = L & 511;
        int soff = row * 512 + (inrow ^ ((row & 7) << 4));
        __builtin_amdgcn_global_load_lds((gas_ptr)(base + soff), (las_ptr)(lb + L),
                                         16, 0, 0);
    }
}

// fragment read: lane holds row (lane&15), k = (lane>>4)*8 + kk*32 .. +8
__device__ __forceinline__ bf16x8 lds_frag(const unsigned short* lds, int row, int kk, int lane) {
    int kbyte = ((lane >> 4) << 4) + (kk << 6);
    int phys = (row * 512 + kbyte) ^ ((row & 7) << 4);
    return *reinterpret_cast<const bf16x8*>(reinterpret_cast<const char*>(lds) + phys);
}

// ---------------- fused sim + online sum-exp + pos extraction ----------------
// 4 waves as 2x2 grid: wave owns 64 rows x 64 cols. A (64 rows, full K=256) in regs.
__global__ __launch_bounds__(256, 2)
void sim_lse_kernel(const unsigned short* __restrict__ Zb,
                    float* __restrict__ partials,   // [NCS][MM]
                    float* __restrict__ posArr) {   // [MM]
    __shared__ unsigned short ldsT[BM * DDIM];      // 64 KB
    __shared__ float ldsRed[4][64];                 // col-partner combine
    const int tid = threadIdx.x;
    const int lane = tid & 63;
    const int w = tid >> 6;
    const int wr = w >> 1, wc = w & 1;              // wave row/col in 2x2
    const int rt = blockIdx.x >> 3;                 // row tile 0..63
    const int cs = blockIdx.x & 7;                  // col split 0..7
    const int R0 = rt * BM;

    // stage Q rows once, pull A-fragments into registers (64 rows x full K)
    stage_tile(Zb, ldsT, R0, tid);
    __syncthreads();
    bf16x8 qf[4][8];
    #pragma unroll
    for (int mf = 0; mf < 4; ++mf)
        #pragma unroll
        for (int kk = 0; kk < 8; ++kk)
            qf[mf][kk] = lds_frag(ldsT, wr * 64 + mf * 16 + (lane & 15), kk, lane);
    __syncthreads();

    float rowsum[4][4] = {{0,0,0,0},{0,0,0,0},{0,0,0,0},{0,0,0,0}};
    const int iBase = R0 + wr * 64 + ((lane >> 4) << 2);  // C/D: row=(lane>>4)*4+r

    for (int ct = 0; ct < TILES_PER_SPLIT; ++ct) {
        const int C0 = cs * COLS_PER_SPLIT + ct * BN;
        stage_tile(Zb, ldsT, C0, tid);
        __syncthreads();
        #pragma unroll
        for (int nf = 0; nf < 4; ++nf) {
            f32x4 acc[4] = {{0,0,0,0},{0,0,0,0},{0,0,0,0},{0,0,0,0}};
            #pragma unroll
            for (int kk = 0; kk < 8; ++kk) {
                bf16x8 b = lds_frag(ldsT, wc * 64 + nf * 16 + (lane & 15), kk, lane);
                #pragma unroll
                for (int mf = 0; mf < 4; ++mf)
                    acc[mf] = __builtin_amdgcn_mfma_f32_16x16x32_bf16(qf[mf][kk], b, acc[mf], 0, 0, 0);
            }
            const int j = C0 + wc * 64 + nf * 16 + (lane & 15);  // C/D: col=lane&15
            #pragma unroll
            for (int mf = 0; mf < 4; ++mf)
                #pragma unroll
                for (int r = 0; r < 4; ++r) {
                    const int i = iBase + mf * 16 + r;
                    const int pc = i < NROWS ? i + NROWS : i - NROWS;
                    // exp(sim - 5) = 2^(a*5*log2e - 5*log2e); skip diagonal
                    if (j != i) rowsum[mf][r] += __builtin_amdgcn_exp2f(fmaf(acc[mf][r], C5L2E, -C5L2E));
                    if (j == pc) posArr[i] = acc[mf][r] * TINV;  // unique writer
                }
        }
        __syncthreads();
    }

    // reduce partial row-sums across the 16 lanes sharing each row
    #pragma unroll
    for (int mf = 0; mf < 4; ++mf)
        #pragma unroll
        for (int r = 0; r < 4; ++r) {
            float s = rowsum[mf][r];
            s += __shfl_xor(s, 1, 64);
            s += __shfl_xor(s, 2, 64);
            s += __shfl_xor(s, 4, 64);
            s += __shfl_xor(s, 8, 64);
            if ((lane & 15) == 0)
                ldsRed[w][mf * 16 + ((lane >> 4) << 2) + r] = s;
        }
    __syncthreads();
    // combine the two col-partner waves, one writer per row
    if (wc == 0) {
        float s = ldsRed[w][lane] + ldsRed[w + 1][lane];
        partials[cs * MM + R0 + wr * 64 + lane] = s;   // unique slot
    }
}

// ---------------- finish: lse = log(sum)+5; mean(lse - pos) ----------------
__global__ __launch_bounds__(128)
void fin1_kernel(const float* __restrict__ partials, const float* __restrict__ posArr,
                 float* __restrict__ blockSums) {    // [64]
    const int tid = threadIdx.x;                     // 128 threads, 1 row each
    const int i = blockIdx.x * 128 + tid;
    float se = 0.f;
    #pragma unroll
    for (int c = 0; c < NCS; ++c) se += partials[c * MM + i];
    double v = (double)(logf(se) + 5.0f - posArr[i]);
    #pragma unroll
    for (int m = 1; m < 64; m <<= 1) v += __shfl_xor(v, m, 64);
    __shared__ double red[2];
    if ((tid & 63) == 0) red[tid >> 6] = v;
    __syncthreads();
    if (tid == 0) blockSums[blockIdx.x] = (float)(red[0] + red[1]);
}

__global__ __launch_bounds__(64)
void fin2_kernel(const float* __restrict__ blockSums, float* __restrict__ out) {
    double v = (double)blockSums[threadIdx.x];
    #pragma unroll
    for (int m = 1; m < 64; m <<= 1) v += __shfl_xor(v, m, 64);
    if (threadIdx.x == 0) out[0] = (float)(v / (double)MM);
}

extern "C" void kernel_launch(void* const* d_in, const int* in_sizes, int n_in,
                              void* d_out, int out_size, void* d_ws, size_t ws_size,
                              hipStream_t stream) {
    const float* Z1 = (const float*)d_in[0];
    const float* Z2 = (const float*)d_in[1];
    float* out = (float*)d_out;
    char* ws = (char*)d_ws;
    unsigned short* Zb = (unsigned short*)ws;                        // 4 MB bf16 [8192][256]
    float* posArr = (float*)(ws + (size_t)MM * DDIM * 2);            // 32 KB
    float* partials = (float*)(ws + (size_t)MM * DDIM * 2 + MM * 4); // 256 KB
    float* blockSums = (float*)(ws + (size_t)MM * DDIM * 2 + MM * 4 + NCS * MM * 4); // 256 B

    nrm_kernel<<<MM / 4, 256, 0, stream>>>(Z1, Z2, Zb);
    sim_lse_kernel<<<64 * NCS, 256, 0, stream>>>(Zb, partials, posArr);
    fin1_kernel<<<64, 128, 0, stream>>>(partials, posArr, blockSums);
    fin2_kernel<<<1, 64, 0, stream>>>(blockSums, out);
}

// Round 4
// 74.491 us; speedup vs baseline: 1.1839x; 1.1839x over previous
//
#include <hip/hip_runtime.h>
#include <cstdint>
#include <cstddef>

#define TINV 5.0f
#define C5L2E 7.2134752044448170f   // 5 * log2(e)
#define NROWS 4096
#define DDIM 256
#define MM 8192
#define BM 128
#define BN 128
#define NCS 8
#define COLS_PER_SPLIT 1024
#define TILES_PER_SPLIT 8

typedef __bf16 bf16x8 __attribute__((ext_vector_type(8)));
typedef float f32x4 __attribute__((ext_vector_type(4)));

typedef const void __attribute__((address_space(1)))* gas_ptr;
typedef void __attribute__((address_space(3)))* las_ptr;

// ---------------- normalize: rows of [Z1;Z2] -> unit L2, store bf16 ----------------
__global__ __launch_bounds__(256, 2)
void nrm_kernel(const float* __restrict__ Z1, const float* __restrict__ Z2,
                unsigned short* __restrict__ Zb) {
    const int w = threadIdx.x >> 6, lane = threadIdx.x & 63;
    const int row = blockIdx.x * 4 + w;
    const float* src = row < NROWS ? Z1 + (size_t)row * DDIM
                                   : Z2 + (size_t)(row - NROWS) * DDIM;
    float4 v = reinterpret_cast<const float4*>(src)[lane];
    float ss = v.x*v.x + v.y*v.y + v.z*v.z + v.w*v.w;
    #pragma unroll
    for (int m = 1; m < 64; m <<= 1) ss += __shfl_xor(ss, m, 64);
    float inv = 1.0f / fmaxf(sqrtf(ss), 1e-12f);
    float o[4] = { v.x*inv, v.y*inv, v.z*inv, v.w*inv };
    unsigned short us[4];
    #pragma unroll
    for (int e = 0; e < 4; ++e) {           // RNE f32->bf16 (finite inputs)
        unsigned int b = __builtin_bit_cast(unsigned int, o[e]);
        b += 0x7FFFu + ((b >> 16) & 1u);
        us[e] = (unsigned short)(b >> 16);
    }
    reinterpret_cast<ushort4*>(Zb + (size_t)row * DDIM)[lane] =
        *reinterpret_cast<ushort4*>(us);
}

// ---- stage 128 rows x 256 cols bf16 (64KB contiguous) into LDS, XOR-swizzled ----
// LDS dest linear (global_load_lds requirement); global SOURCE pre-swizzled so
// reads with phys = lin ^ ((row&15)<<4) see the correct data (16-slot spread).
__device__ __forceinline__ void stage_tile(const unsigned short* Zb, unsigned short* lds,
                                           int rowStart, int tid) {
    const char* base = reinterpret_cast<const char*>(Zb) + (size_t)rowStart * 512;
    char* lb = reinterpret_cast<char*>(lds);
    #pragma unroll
    for (int it = 0; it < 16; ++it) {
        int L = it * 4096 + tid * 16;     // linear LDS byte offset, lane-contiguous
        int row = L >> 9;                 // 0..127 (512 B per row)
        int inrow = L & 511;
        int soff = row * 512 + (inrow ^ ((row & 15) << 4));
        __builtin_amdgcn_global_load_lds((gas_ptr)(base + soff), (las_ptr)(lb + L),
                                         16, 0, 0);
    }
}

// fragment read: lane holds row (lane&15), k = (lane>>4)*8 + kk*32 .. +8
__device__ __forceinline__ bf16x8 lds_frag(const unsigned short* lds, int row, int kk, int lane) {
    int kbyte = ((lane >> 4) << 4) + (kk << 6);
    int phys = row * 512 + (kbyte ^ ((row & 15) << 4));
    return *reinterpret_cast<const bf16x8*>(reinterpret_cast<const char*>(lds) + phys);
}

// ---------------- fused sim + online sum-exp + pos extraction ----------------
// 4 waves as 2x2 grid: wave owns 64 rows x 64 cols. A (64 rows, full K=256) in regs.
// waves_per_eu(2,2): LDS caps us at 2 blocks/CU anyway; give allocator 256-VGPR budget.
__global__ __launch_bounds__(256)
__attribute__((amdgpu_waves_per_eu(2, 2)))
void sim_lse_kernel(const unsigned short* __restrict__ Zb,
                    float* __restrict__ partials,   // [NCS][MM]
                    float* __restrict__ posArr) {   // [MM]
    __shared__ unsigned short ldsT[BM * DDIM];      // 64 KB
    __shared__ float ldsRed[4][64];                 // col-partner combine
    const int tid = threadIdx.x;
    const int lane = tid & 63;
    const int w = tid >> 6;
    const int wr = w >> 1, wc = w & 1;              // wave row/col in 2x2
    const int rt = blockIdx.x >> 3;                 // row tile 0..63
    const int cs = blockIdx.x & 7;                  // col split 0..7
    const int R0 = rt * BM;

    // stage Q rows once, pull A-fragments into registers (64 rows x full K)
    stage_tile(Zb, ldsT, R0, tid);
    __syncthreads();
    bf16x8 qf[4][8];
    #pragma unroll
    for (int mf = 0; mf < 4; ++mf)
        #pragma unroll
        for (int kk = 0; kk < 8; ++kk)
            qf[mf][kk] = lds_frag(ldsT, wr * 64 + mf * 16 + (lane & 15), kk, lane);
    __syncthreads();

    float rowsum[4][4] = {{0,0,0,0},{0,0,0,0},{0,0,0,0},{0,0,0,0}};
    const int iBase = R0 + wr * 64 + ((lane >> 4) << 2);  // C/D: row=(lane>>4)*4+r

    for (int ct = 0; ct < TILES_PER_SPLIT; ++ct) {
        const int C0 = cs * COLS_PER_SPLIT + ct * BN;
        stage_tile(Zb, ldsT, C0, tid);
        __syncthreads();
        #pragma unroll
        for (int nf = 0; nf < 4; ++nf) {
            f32x4 acc[4] = {{0,0,0,0},{0,0,0,0},{0,0,0,0},{0,0,0,0}};
            #pragma unroll
            for (int kk = 0; kk < 8; ++kk) {
                bf16x8 b = lds_frag(ldsT, wc * 64 + nf * 16 + (lane & 15), kk, lane);
                #pragma unroll
                for (int mf = 0; mf < 4; ++mf)
                    acc[mf] = __builtin_amdgcn_mfma_f32_16x16x32_bf16(qf[mf][kk], b, acc[mf], 0, 0, 0);
            }
            const int j = C0 + wc * 64 + nf * 16 + (lane & 15);  // C/D: col=lane&15
            #pragma unroll
            for (int mf = 0; mf < 4; ++mf)
                #pragma unroll
                for (int r = 0; r < 4; ++r) {
                    const int i = iBase + mf * 16 + r;
                    const int pc = i < NROWS ? i + NROWS : i - NROWS;
                    // exp(sim - 5) = 2^(a*5*log2e - 5*log2e); skip diagonal
                    if (j != i) rowsum[mf][r] += __builtin_amdgcn_exp2f(fmaf(acc[mf][r], C5L2E, -C5L2E));
                    if (j == pc) posArr[i] = acc[mf][r] * TINV;  // unique writer
                }
        }
        __syncthreads();
    }

    // reduce partial row-sums across the 16 lanes sharing each row
    #pragma unroll
    for (int mf = 0; mf < 4; ++mf)
        #pragma unroll
        for (int r = 0; r < 4; ++r) {
            float s = rowsum[mf][r];
            s += __shfl_xor(s, 1, 64);
            s += __shfl_xor(s, 2, 64);
            s += __shfl_xor(s, 4, 64);
            s += __shfl_xor(s, 8, 64);
            if ((lane & 15) == 0)
                ldsRed[w][mf * 16 + ((lane >> 4) << 2) + r] = s;
        }
    __syncthreads();
    // combine the two col-partner waves, one writer per row
    if (wc == 0) {
        float s = ldsRed[w][lane] + ldsRed[w + 1][lane];
        partials[cs * MM + R0 + wr * 64 + lane] = s;   // unique slot
    }
}

// ---------------- finish: lse = log(sum)+5; mean(lse - pos) ----------------
__global__ __launch_bounds__(128)
void fin1_kernel(const float* __restrict__ partials, const float* __restrict__ posArr,
                 float* __restrict__ blockSums) {    // [64]
    const int tid = threadIdx.x;                     // 128 threads, 1 row each
    const int i = blockIdx.x * 128 + tid;
    float se = 0.f;
    #pragma unroll
    for (int c = 0; c < NCS; ++c) se += partials[c * MM + i];
    double v = (double)(logf(se) + 5.0f - posArr[i]);
    #pragma unroll
    for (int m = 1; m < 64; m <<= 1) v += __shfl_xor(v, m, 64);
    __shared__ double red[2];
    if ((tid & 63) == 0) red[tid >> 6] = v;
    __syncthreads();
    if (tid == 0) blockSums[blockIdx.x] = (float)(red[0] + red[1]);
}

__global__ __launch_bounds__(64)
void fin2_kernel(const float* __restrict__ blockSums, float* __restrict__ out) {
    double v = (double)blockSums[threadIdx.x];
    #pragma unroll
    for (int m = 1; m < 64; m <<= 1) v += __shfl_xor(v, m, 64);
    if (threadIdx.x == 0) out[0] = (float)(v / (double)MM);
}

extern "C" void kernel_launch(void* const* d_in, const int* in_sizes, int n_in,
                              void* d_out, int out_size, void* d_ws, size_t ws_size,
                              hipStream_t stream) {
    const float* Z1 = (const float*)d_in[0];
    const float* Z2 = (const float*)d_in[1];
    float* out = (float*)d_out;
    char* ws = (char*)d_ws;
    unsigned short* Zb = (unsigned short*)ws;                        // 4 MB bf16 [8192][256]
    float* posArr = (float*)(ws + (size_t)MM * DDIM * 2);            // 32 KB
    float* partials = (float*)(ws + (size_t)MM * DDIM * 2 + MM * 4); // 256 KB
    float* blockSums = (float*)(ws + (size_t)MM * DDIM * 2 + MM * 4 + NCS * MM * 4); // 256 B

    nrm_kernel<<<MM / 4, 256, 0, stream>>>(Z1, Z2, Zb);
    sim_lse_kernel<<<64 * NCS, 256, 0, stream>>>(Zb, partials, posArr);
    fin1_kernel<<<64, 128, 0, stream>>>(partials, posArr, blockSums);
    fin2_kernel<<<1, 64, 0, stream>>>(blockSums, out);
}

// Round 5
// 52.362 us; speedup vs baseline: 1.6843x; 1.4226x over previous
//
#include <hip/hip_runtime.h>
#include <cstdint>
#include <cstddef>

#define TINV 5.0f
#define C5L2E 7.2134752044448170f   // 5 * log2(e)
#define NROWS 4096
#define DDIM 256
#define MM 8192
#define BM 128
#define NCS 8

typedef __bf16 bf16x8 __attribute__((ext_vector_type(8)));
typedef float f32x4 __attribute__((ext_vector_type(4)));

typedef const void __attribute__((address_space(1)))* gas_ptr;
typedef void __attribute__((address_space(3)))* las_ptr;

// ---------------- normalize: rows of [Z1;Z2] -> unit L2, store bf16 ----------------
__global__ __launch_bounds__(256, 2)
void nrm_kernel(const float* __restrict__ Z1, const float* __restrict__ Z2,
                unsigned short* __restrict__ Zb) {
    const int w = threadIdx.x >> 6, lane = threadIdx.x & 63;
    const int row = blockIdx.x * 4 + w;
    const float* src = row < NROWS ? Z1 + (size_t)row * DDIM
                                   : Z2 + (size_t)(row - NROWS) * DDIM;
    float4 v = reinterpret_cast<const float4*>(src)[lane];
    float ss = v.x*v.x + v.y*v.y + v.z*v.z + v.w*v.w;
    #pragma unroll
    for (int m = 1; m < 64; m <<= 1) ss += __shfl_xor(ss, m, 64);
    float inv = 1.0f / fmaxf(sqrtf(ss), 1e-12f);
    float o[4] = { v.x*inv, v.y*inv, v.z*inv, v.w*inv };
    unsigned short us[4];
    #pragma unroll
    for (int e = 0; e < 4; ++e) {           // RNE f32->bf16 (finite inputs)
        unsigned int b = __builtin_bit_cast(unsigned int, o[e]);
        b += 0x7FFFu + ((b >> 16) & 1u);
        us[e] = (unsigned short)(b >> 16);
    }
    reinterpret_cast<ushort4*>(Zb + (size_t)row * DDIM)[lane] =
        *reinterpret_cast<ushort4*>(us);
}

// ---- stage 64 rows x 512B (32KB) into LDS; source pre-swizzled, LDS linear ----
// read side uses phys_inrow = inrow ^ ((row&15)<<4)
__device__ __forceinline__ void stage32(const unsigned short* Zb, char* ldsdst,
                                        int rowStart, int tid) {
    const char* base = reinterpret_cast<const char*>(Zb) + (size_t)rowStart * 512;
    #pragma unroll
    for (int it = 0; it < 8; ++it) {
        int L = it * 4096 + tid * 16;     // linear LDS byte offset, lane-contiguous
        int row = L >> 9;                 // 0..63
        int soff = row * 512 + ((L & 511) ^ ((row & 15) << 4));
        __builtin_amdgcn_global_load_lds((gas_ptr)(base + soff), (las_ptr)(ldsdst + L),
                                         16, 0, 0);
    }
}

// ---------------- fused sim + online sum-exp + pos extraction ----------------
// 4 waves; wave owns 32 rows x all 64 cols of each B tile. A (32 rows, K=256) in regs.
// B tiles (64 cols x 256 K = 32KB) double-buffered, counted-vmcnt pipeline.
__global__ __launch_bounds__(256, 2)
void sim_lse_kernel(const unsigned short* __restrict__ Zb,
                    float* __restrict__ partials,   // [NCS][MM]
                    float* __restrict__ posArr) {   // [MM]
    __shared__ char lds[65536];                     // 2 x 32KB buffers
    const int tid = threadIdx.x;
    const int lane = tid & 63;
    const int w = tid >> 6;
    const int r15 = lane & 15, hi = lane >> 4;
    const int rt = blockIdx.x >> 3;                 // row tile 0..63
    const int cs = blockIdx.x & 7;                  // col split 0..7
    const int R0 = rt * BM;
    const int P0 = R0 ^ 4096;                       // pos-partner 128-row band

    // thread-constant swizzled k-chunk offsets: row&15 == r15 for every frag read
    int koff[8];
    #pragma unroll
    for (int kk = 0; kk < 8; ++kk)
        koff[kk] = ((hi << 4) | (kk << 6)) ^ (r15 << 4);

    // ---- stage A (128 rows) across both buffers, pull frags to registers ----
    stage32(Zb, lds, R0, tid);
    stage32(Zb, lds + 32768, R0 + 64, tid);
    __syncthreads();
    bf16x8 qf[2][8];
    {
        const char* ab = lds + ((w >> 1) << 15);
        #pragma unroll
        for (int mf = 0; mf < 2; ++mf)
            #pragma unroll
            for (int kk = 0; kk < 8; ++kk)
                qf[mf][kk] = *reinterpret_cast<const bf16x8*>(
                    ab + ((w & 1) * 32 + mf * 16 + r15) * 512 + koff[kk]);
    }
    __syncthreads();

    // per-thread B-frag base offsets (buffer/nf selected via immediates)
    int baddr[8];
    #pragma unroll
    for (int kk = 0; kk < 8; ++kk) baddr[kk] = r15 * 512 + koff[kk];

    float rowsum[2][4] = {{0,0,0,0},{0,0,0,0}};
    const int iBase = R0 + w * 32 + (hi << 2);      // C/D: row=(lane>>4)*4+r

    stage32(Zb, lds, cs * 1024, tid);               // tile 0 -> buf0

    for (int ct = 0; ct < 16; ++ct) {
        const int C0 = cs * 1024 + ct * 64;
        const int cur = (ct & 1) << 15;
        if (ct < 15) {
            stage32(Zb, lds + (cur ^ 32768), C0 + 64, tid);
            asm volatile("s_waitcnt vmcnt(8)" ::: "memory");   // cur's 8 loads done
        } else {
            asm volatile("s_waitcnt vmcnt(0)" ::: "memory");
        }
        __builtin_amdgcn_s_barrier();
        __builtin_amdgcn_sched_barrier(0);

        const bool special = ((C0 & ~127) == R0) || ((C0 & ~127) == P0);
        #pragma unroll
        for (int nf = 0; nf < 4; ++nf) {
            f32x4 acc0 = {0,0,0,0}, acc1 = {0,0,0,0};
            #pragma unroll
            for (int kk = 0; kk < 8; ++kk) {
                bf16x8 b = *reinterpret_cast<const bf16x8*>(lds + cur + nf * 8192 + baddr[kk]);
                acc0 = __builtin_amdgcn_mfma_f32_16x16x32_bf16(qf[0][kk], b, acc0, 0, 0, 0);
                acc1 = __builtin_amdgcn_mfma_f32_16x16x32_bf16(qf[1][kk], b, acc1, 0, 0, 0);
            }
            const int j = C0 + nf * 16 + r15;       // C/D: col=lane&15
            if (special) {
                #pragma unroll
                for (int mf = 0; mf < 2; ++mf) {
                    const f32x4 a = mf ? acc1 : acc0;
                    #pragma unroll
                    for (int r = 0; r < 4; ++r) {
                        const int i = iBase + mf * 16 + r;
                        if (j != i) rowsum[mf][r] += __builtin_amdgcn_exp2f(fmaf(a[r], C5L2E, -C5L2E));
                        if (j == (i ^ 4096)) posArr[i] = a[r] * TINV;   // unique writer
                    }
                }
            } else {
                #pragma unroll
                for (int mf = 0; mf < 2; ++mf) {
                    const f32x4 a = mf ? acc1 : acc0;
                    #pragma unroll
                    for (int r = 0; r < 4; ++r)
                        rowsum[mf][r] += __builtin_amdgcn_exp2f(fmaf(a[r], C5L2E, -C5L2E));
                }
            }
        }
        asm volatile("" ::: "memory");
        __builtin_amdgcn_sched_barrier(0);
        __builtin_amdgcn_s_barrier();               // done reading cur before overwrite
    }

    // reduce partial row-sums across the 16 lanes sharing each row
    #pragma unroll
    for (int mf = 0; mf < 2; ++mf)
        #pragma unroll
        for (int r = 0; r < 4; ++r) {
            float s = rowsum[mf][r];
            s += __shfl_xor(s, 1, 64);
            s += __shfl_xor(s, 2, 64);
            s += __shfl_xor(s, 4, 64);
            s += __shfl_xor(s, 8, 64);
            if (r15 == 0)
                partials[cs * MM + iBase + mf * 16 + r] = s;  // unique slot
        }
}

// ---------------- finish: lse = log(sum)+5; mean(lse - pos) ----------------
__global__ __launch_bounds__(128)
void fin1_kernel(const float* __restrict__ partials, const float* __restrict__ posArr,
                 float* __restrict__ blockSums) {    // [64]
    const int tid = threadIdx.x;                     // 128 threads, 1 row each
    const int i = blockIdx.x * 128 + tid;
    float se = 0.f;
    #pragma unroll
    for (int c = 0; c < NCS; ++c) se += partials[c * MM + i];
    double v = (double)(logf(se) + 5.0f - posArr[i]);
    #pragma unroll
    for (int m = 1; m < 64; m <<= 1) v += __shfl_xor(v, m, 64);
    __shared__ double red[2];
    if ((tid & 63) == 0) red[tid >> 6] = v;
    __syncthreads();
    if (tid == 0) blockSums[blockIdx.x] = (float)(red[0] + red[1]);
}

__global__ __launch_bounds__(64)
void fin2_kernel(const float* __restrict__ blockSums, float* __restrict__ out) {
    double v = (double)blockSums[threadIdx.x];
    #pragma unroll
    for (int m = 1; m < 64; m <<= 1) v += __shfl_xor(v, m, 64);
    if (threadIdx.x == 0) out[0] = (float)(v / (double)MM);
}

extern "C" void kernel_launch(void* const* d_in, const int* in_sizes, int n_in,
                              void* d_out, int out_size, void* d_ws, size_t ws_size,
                              hipStream_t stream) {
    const float* Z1 = (const float*)d_in[0];
    const float* Z2 = (const float*)d_in[1];
    float* out = (float*)d_out;
    char* ws = (char*)d_ws;
    unsigned short* Zb = (unsigned short*)ws;                        // 4 MB bf16 [8192][256]
    float* posArr = (float*)(ws + (size_t)MM * DDIM * 2);            // 32 KB
    float* partials = (float*)(ws + (size_t)MM * DDIM * 2 + MM * 4); // 256 KB
    float* blockSums = (float*)(ws + (size_t)MM * DDIM * 2 + MM * 4 + NCS * MM * 4); // 256 B

    nrm_kernel<<<MM / 4, 256, 0, stream>>>(Z1, Z2, Zb);
    sim_lse_kernel<<<64 * NCS, 256, 0, stream>>>(Zb, partials, posArr);
    fin1_kernel<<<64, 128, 0, stream>>>(partials, posArr, blockSums);
    fin2_kernel<<<1, 64, 0, stream>>>(blockSums, out);
}

// Round 6
// 44.518 us; speedup vs baseline: 1.9810x; 1.1762x over previous
//
#include <hip/hip_runtime.h>
#include <cstdint>
#include <cstddef>

#define TINV 5.0f
#define C5L2E 7.2134752044448170f   // 5 * log2(e)
#define NROWS 4096
#define DDIM 256
#define MM 8192

typedef __bf16 bf16x8 __attribute__((ext_vector_type(8)));
typedef float f32x4 __attribute__((ext_vector_type(4)));

typedef const void __attribute__((address_space(1)))* gas_ptr;
typedef void __attribute__((address_space(3)))* las_ptr;

// ------- normalize rows of [Z1;Z2] -> unit L2, store bf16; zero rowsumAcc -------
__global__ __launch_bounds__(256, 2)
void nrm_kernel(const float* __restrict__ Z1, const float* __restrict__ Z2,
                unsigned short* __restrict__ Zb, float* __restrict__ rowsumAcc) {
    if (blockIdx.x < 32) rowsumAcc[blockIdx.x * 256 + threadIdx.x] = 0.f;
    const int w = threadIdx.x >> 6, lane = threadIdx.x & 63;
    const int row = blockIdx.x * 4 + w;
    const float* src = row < NROWS ? Z1 + (size_t)row * DDIM
                                   : Z2 + (size_t)(row - NROWS) * DDIM;
    float4 v = reinterpret_cast<const float4*>(src)[lane];
    float ss = v.x*v.x + v.y*v.y + v.z*v.z + v.w*v.w;
    #pragma unroll
    for (int m = 1; m < 64; m <<= 1) ss += __shfl_xor(ss, m, 64);
    float inv = 1.0f / fmaxf(sqrtf(ss), 1e-12f);
    float o[4] = { v.x*inv, v.y*inv, v.z*inv, v.w*inv };
    unsigned short us[4];
    #pragma unroll
    for (int e = 0; e < 4; ++e) {           // RNE f32->bf16 (finite inputs)
        unsigned int b = __builtin_bit_cast(unsigned int, o[e]);
        b += 0x7FFFu + ((b >> 16) & 1u);
        us[e] = (unsigned short)(b >> 16);
    }
    reinterpret_cast<ushort4*>(Zb + (size_t)row * DDIM)[lane] =
        *reinterpret_cast<ushort4*>(us);
}

// ---- stage 64 rows x 512B (32KB) into LDS; source pre-swizzled, LDS linear ----
// read side uses phys_inrow = inrow ^ ((row&15)<<4)
__device__ __forceinline__ void stage32(const unsigned short* Zb, char* ldsdst,
                                        int rowStart, int tid) {
    const char* base = reinterpret_cast<const char*>(Zb) + (size_t)rowStart * 512;
    #pragma unroll
    for (int it = 0; it < 8; ++it) {
        int L = it * 4096 + tid * 16;     // linear LDS byte offset, lane-contiguous
        int row = L >> 9;                 // 0..63
        int soff = row * 512 + ((L & 511) ^ ((row & 15) << 4));
        __builtin_amdgcn_global_load_lds((gas_ptr)(base + soff), (las_ptr)(ldsdst + L),
                                         16, 0, 0);
    }
}

// -------- symmetric fused sim + exp-rowsum/colsum + pos extraction --------
// Bands of 128 rows (64 bands). Block (r,s): band r, d-offsets {s,s+8,s+16,s+24}
// (each a 128x128 tile vs band (r+d)%64, processed as 2 x 64-col subtiles),
// plus (for 2 of 8 splits) one half of the d=32 tile (rowsum-only, pos lives here).
// d=0: diagonal tile, rowsum-only with j==i skip. d=1..31: rowsum AND colsum
// (symmetry: col sums of the tile = row-sum contributions for band (r+d)).
__global__ __launch_bounds__(256, 2)
void sim_lse_kernel(const unsigned short* __restrict__ Zb,
                    float* __restrict__ rowsumAcc,  // [MM], atomic accum
                    float* __restrict__ posArr) {   // [MM]
    __shared__ char lds[65536];                     // 2 x 32KB B buffers
    __shared__ float colRed[4][128];
    const int tid = threadIdx.x;
    const int lane = tid & 63;
    const int w = tid >> 6;
    const int r15 = lane & 15, hi = lane >> 4;
    const int r = blockIdx.x >> 3;                  // band 0..63
    const int s = blockIdx.x & 7;                   // split 0..7
    const int e0 = r & 7, e1 = e0 ^ 4;              // which splits take d=32 halves
    const int nt = 8 + ((s == e0) || (s == e1));
    const int extraHalf = (s == e1) ? 1 : 0;
    const int R0 = r * 128;

    // thread-constant swizzled k-chunk offsets (row&15 == r15 for every frag read)
    int koff[8];
    #pragma unroll
    for (int kk = 0; kk < 8; ++kk)
        koff[kk] = ((hi << 4) | (kk << 6)) ^ (r15 << 4);

    // ---- stage A band (128 rows) across both buffers, pull frags to registers ----
    stage32(Zb, lds, R0, tid);
    stage32(Zb, lds + 32768, R0 + 64, tid);
    __syncthreads();
    bf16x8 qf[2][8];
    {
        const char* ab = lds + ((w >> 1) << 15);
        #pragma unroll
        for (int mf = 0; mf < 2; ++mf)
            #pragma unroll
            for (int kk = 0; kk < 8; ++kk)
                qf[mf][kk] = *reinterpret_cast<const bf16x8*>(
                    ab + ((w & 1) * 32 + mf * 16 + r15) * 512 + koff[kk]);
    }
    __syncthreads();

    int baddr[8];
    #pragma unroll
    for (int kk = 0; kk < 8; ++kk) baddr[kk] = r15 * 512 + koff[kk];

    float rowsum[2][4] = {{0,0,0,0},{0,0,0,0}};
    const int iBase = R0 + w * 32 + (hi << 2);      // C/D: row=(lane>>4)*4+rr

    // column start (Zb row units) of subtile step t
    auto colOf = [&](int t) -> int {
        int d = (t < 8) ? (s + ((t >> 1) << 3)) : 32;
        int half = (t < 8) ? (t & 1) : extraHalf;
        return ((r + d) & 63) * 128 + half * 64;
    };

    stage32(Zb, lds, colOf(0), tid);                // subtile 0 -> buf0

    for (int t = 0; t < nt; ++t) {
        const int C0 = colOf(t);
        const int cur = (t & 1) << 15;
        if (t < nt - 1) {
            stage32(Zb, lds + (cur ^ 32768), colOf(t + 1), tid);
            asm volatile("s_waitcnt vmcnt(8)" ::: "memory");   // cur's 8 loads done
        } else {
            asm volatile("s_waitcnt vmcnt(0)" ::: "memory");
        }
        __builtin_amdgcn_s_barrier();
        __builtin_amdgcn_sched_barrier(0);

        const int mode = (t == 8) ? 2 : ((s == 0 && t < 2) ? 1 : 0); // 0 norm,1 diag,2 pos
        #pragma unroll
        for (int nf = 0; nf < 4; ++nf) {
            f32x4 acc0 = {0,0,0,0}, acc1 = {0,0,0,0};
            #pragma unroll
            for (int kk = 0; kk < 8; ++kk) {
                bf16x8 b = *reinterpret_cast<const bf16x8*>(lds + cur + nf * 8192 + baddr[kk]);
                acc0 = __builtin_amdgcn_mfma_f32_16x16x32_bf16(qf[0][kk], b, acc0, 0, 0, 0);
                acc1 = __builtin_amdgcn_mfma_f32_16x16x32_bf16(qf[1][kk], b, acc1, 0, 0, 0);
            }
            const int j = C0 + nf * 16 + r15;       // C/D: col=lane&15
            if (mode == 0) {
                float s8 = 0.f;
                #pragma unroll
                for (int mf = 0; mf < 2; ++mf) {
                    const f32x4 a = mf ? acc1 : acc0;
                    #pragma unroll
                    for (int rr = 0; rr < 4; ++rr) {
                        float e = __builtin_amdgcn_exp2f(fmaf(a[rr], C5L2E, -C5L2E));
                        rowsum[mf][rr] += e;
                        s8 += e;
                    }
                }
                s8 += __shfl_xor(s8, 16, 64);       // sum the 4 hi-groups (32 rows)
                s8 += __shfl_xor(s8, 32, 64);
                if (hi == 0) colRed[w][(t & 1) * 64 + nf * 16 + r15] = s8;
            } else if (mode == 1) {
                #pragma unroll
                for (int mf = 0; mf < 2; ++mf) {
                    const f32x4 a = mf ? acc1 : acc0;
                    #pragma unroll
                    for (int rr = 0; rr < 4; ++rr) {
                        const int i = iBase + mf * 16 + rr;
                        if (j != i)
                            rowsum[mf][rr] += __builtin_amdgcn_exp2f(fmaf(a[rr], C5L2E, -C5L2E));
                    }
                }
            } else {
                #pragma unroll
                for (int mf = 0; mf < 2; ++mf) {
                    const f32x4 a = mf ? acc1 : acc0;
                    #pragma unroll
                    for (int rr = 0; rr < 4; ++rr) {
                        const int i = iBase + mf * 16 + rr;
                        rowsum[mf][rr] += __builtin_amdgcn_exp2f(fmaf(a[rr], C5L2E, -C5L2E));
                        if (j == (i ^ 4096)) posArr[i] = a[rr] * TINV;  // unique writer
                    }
                }
            }
        }
        asm volatile("" ::: "memory");
        __builtin_amdgcn_sched_barrier(0);
        __builtin_amdgcn_s_barrier();               // done reading cur before overwrite

        // after both halves of a normal-mode d: flush colsums to band (r+d)
        if ((t & 1) == 1 && !(s == 0 && t == 1)) {
            if (tid < 128) {
                float v = colRed[0][tid] + colRed[1][tid] + colRed[2][tid] + colRed[3][tid];
                const int cc = ((r + s + ((t >> 1) << 3)) & 63) * 128;
                atomicAdd(&rowsumAcc[cc + tid], v);
            }
        }
    }

    // reduce rowsums across the 16 lanes sharing each row, flush atomically
    #pragma unroll
    for (int mf = 0; mf < 2; ++mf)
        #pragma unroll
        for (int rr = 0; rr < 4; ++rr) {
            float v = rowsum[mf][rr];
            v += __shfl_xor(v, 1, 64);
            v += __shfl_xor(v, 2, 64);
            v += __shfl_xor(v, 4, 64);
            v += __shfl_xor(v, 8, 64);
            if (r15 == 0) atomicAdd(&rowsumAcc[iBase + mf * 16 + rr], v);
        }
}

// ---------------- finish: lse = log(sum)+5; mean(lse - pos) ----------------
__global__ __launch_bounds__(128)
void fin1_kernel(const float* __restrict__ rowsumAcc, const float* __restrict__ posArr,
                 float* __restrict__ blockSums) {    // [64]
    const int tid = threadIdx.x;
    const int i = blockIdx.x * 128 + tid;
    double v = (double)(logf(rowsumAcc[i]) + 5.0f - posArr[i]);
    #pragma unroll
    for (int m = 1; m < 64; m <<= 1) v += __shfl_xor(v, m, 64);
    __shared__ double red[2];
    if ((tid & 63) == 0) red[tid >> 6] = v;
    __syncthreads();
    if (tid == 0) blockSums[blockIdx.x] = (float)(red[0] + red[1]);
}

__global__ __launch_bounds__(64)
void fin2_kernel(const float* __restrict__ blockSums, float* __restrict__ out) {
    double v = (double)blockSums[threadIdx.x];
    #pragma unroll
    for (int m = 1; m < 64; m <<= 1) v += __shfl_xor(v, m, 64);
    if (threadIdx.x == 0) out[0] = (float)(v / (double)MM);
}

extern "C" void kernel_launch(void* const* d_in, const int* in_sizes, int n_in,
                              void* d_out, int out_size, void* d_ws, size_t ws_size,
                              hipStream_t stream) {
    const float* Z1 = (const float*)d_in[0];
    const float* Z2 = (const float*)d_in[1];
    float* out = (float*)d_out;
    char* ws = (char*)d_ws;
    unsigned short* Zb = (unsigned short*)ws;                         // 4 MB bf16 [8192][256]
    float* posArr = (float*)(ws + (size_t)MM * DDIM * 2);             // 32 KB
    float* rowsumAcc = (float*)(ws + (size_t)MM * DDIM * 2 + MM * 4); // 32 KB
    float* blockSums = (float*)(ws + (size_t)MM * DDIM * 2 + 2 * MM * 4); // 256 B

    nrm_kernel<<<MM / 4, 256, 0, stream>>>(Z1, Z2, Zb, rowsumAcc);
    sim_lse_kernel<<<64 * 8, 256, 0, stream>>>(Zb, rowsumAcc, posArr);
    fin1_kernel<<<64, 128, 0, stream>>>(rowsumAcc, posArr, blockSums);
    fin2_kernel<<<1, 64, 0, stream>>>(blockSums, out);
}